// Round 1
// baseline (329.192 us; speedup 1.0000x reference)
//
#include <hip/hip_runtime.h>

// MPS classifier, MI355X gfx950. Round 7: split-phi restructure.
// Per site: left' = c_b*(left @ M0) + s_b*(left @ M1)  (two K=128 fp16 GEMMs)
// instead of (left x phi) @ M (one K=256 GEMM). Same FLOPs, but the A operand
// is plain `left` fp16: A-frag LDS bytes halve (8 b128 reads/wave/site, each
// feeding 4 MFMAs), and the epilogue is fma+cvt+ds_write_b16 scatter — no DPP
// transpose, no mul_phi, no b128 LDS round trip. Frag slots are XOR-swizzled
// (phys = S ^ ((S>>3)&7)) on both write and read: b16 scatter is 2-way (free).
// B=8192, N=256, D=128, OUT=10. 256 WGs x 256 threads, wave w owns cols
// [32w,32w+32) of both M0 and M1 products. One barrier/site, A dbuf in LDS,
// B reg ping-pong (16 uint4/buf, unchanged traffic: 64 KB/site/WG, minimal).

typedef _Float16 v8h __attribute__((ext_vector_type(8)));
typedef _Float16 h2  __attribute__((ext_vector_type(2)));
typedef float    v4f __attribute__((ext_vector_type(4)));

#define PI_HALF 1.5707963267948966f
#define SITE_U4 4096   // uint4 per site in wsB: 2 d-planes * 4 kt * 8 ntg * 64 lanes

union U4H8 { uint4 u; v8h h; };

__device__ __forceinline__ v4f mfma16h(uint4 a, uint4 b, v4f c){
  U4H8 ua, ub; ua.u = a; ub.u = b;
  return __builtin_amdgcn_mfma_f32_16x16x32_f16(ua.h, ub.h, c, 0, 0, 0);
}
__device__ __forceinline__ unsigned pack2h(float lo, float hi){
  h2 p; p[0] = (_Float16)lo; p[1] = (_Float16)hi;
  return __builtin_bit_cast(unsigned, p);
}

// ---------------------------------------------------------------------------
// Repack mid (fp32 [254][128][2][128]) -> two fp16 B-matrices per site:
// wsB[site][d][kt(4)][ntg(8)][lane(64)] uint4: element (lane, j) =
//   mid[site][k = 32kt+8(lane>>4)+j][d][n = 16ntg+(lane&15)]   (j = 0..7)
// ---------------------------------------------------------------------------
__global__ __launch_bounds__(256) void repack_mid(const float* __restrict__ mid,
                                                  unsigned short* __restrict__ wsB){
  int idx  = blockIdx.x * 256 + threadIdx.x;   // 254*2*4*8*16 = 260096 threads
  int lg   = idx & 15;
  int nt   = (idx >> 4) & 7;
  int kt   = (idx >> 7) & 3;
  int d    = (idx >> 9) & 1;
  int site = idx >> 10;
  int q    = lg >> 2;
  int n0   = 16*nt + 4*(lg & 3);
  // src: mid[site][32kt+8q+j][d][n0..n0+3]; j-stride = 2*128 floats
  const float* src = mid + ((size_t)(site*128 + 32*kt + 8*q)*2 + d)*128 + n0;
  float V[8][4];
  #pragma unroll
  for (int j = 0; j < 8; ++j){
    float4 a = *(const float4*)(src + (size_t)j*256);
    V[j][0]=a.x; V[j][1]=a.y; V[j][2]=a.z; V[j][3]=a.w;
  }
  uint4* dst = (uint4*)wsB + ((((size_t)site*2 + d)*4 + kt)*8 + nt)*64
             + 16*q + 4*(lg & 3);
  #pragma unroll
  for (int t = 0; t < 4; ++t){
    uint4 o;
    o.x = pack2h(V[0][t], V[1][t]);
    o.y = pack2h(V[2][t], V[3][t]);
    o.z = pack2h(V[4][t], V[5][t]);
    o.w = pack2h(V[6][t], V[7][t]);
    dst[t] = o;
  }
}

// ---------------------------------------------------------------------------
// Main persistent kernel. LDS: phiT[256][36] packed f16 (cos,sin), 36 KB;
// AfragU 2 bufs x 8 KB (K=128 A-frags, XOR-swizzled slots); scal[32].
// A-frag logical layout: slot L of (mt,kt) holds A[16mt+(L&15)][32kt+8(L>>4)+j],
// stored at phys slot L ^ ((L>>3)&7).
// ---------------------------------------------------------------------------
__global__ __launch_bounds__(256, 1) void mps_main(
    const float* __restrict__ x,               // [8192][256]
    const float* __restrict__ first,           // [2][128]
    const unsigned short* __restrict__ wsB,    // repacked mid, fp16 frags
    const float* __restrict__ lastw,           // [128][2]
    const float* __restrict__ wlin,            // [10]
    const float* __restrict__ blin,            // [10]
    float* __restrict__ out)                   // [8192][10]
{
  __shared__ unsigned phiT[256*36];
  __shared__ unsigned AfragU[2*2*4*64*4];      // [buf][mt][kt][slot][word], 16 KB
  __shared__ float scal[32];

  const int tid  = threadIdx.x;
  const int g    = blockIdx.x;
  const int w    = tid >> 6;             // wave 0..3: cols [32w, 32w+32)
  const int lane = tid & 63;
  const int r    = lane & 15;
  const int q    = lane >> 4;
  const int rowbase = g * 32;
  const int physL = lane ^ ((lane >> 3) & 7);        // swizzled own-slot
  const int rh    = r >> 3;
  const int wtail = ((r & 7) >> 1)*2 + (r & 1);      // ushort offset in chunk

  // ---- Phase 1: feature map -> packed f16 (cos,sin) table ----
  {
    const int row = tid >> 3;            // 0..31
    const int c0  = (tid & 7) * 32;      // 32-site chunk
    const float4* xp = (const float4*)(x + (size_t)(rowbase + row) * 256 + c0);
    float xv[32];
    float vmin = 3.0e38f, vmax = -3.0e38f;
    #pragma unroll
    for (int c = 0; c < 8; ++c){
      float4 u = xp[c];
      xv[c*4+0] = u.x; xv[c*4+1] = u.y; xv[c*4+2] = u.z; xv[c*4+3] = u.w;
      vmin = fminf(vmin, fminf(fminf(u.x,u.y), fminf(u.z,u.w)));
      vmax = fmaxf(vmax, fmaxf(fmaxf(u.x,u.y), fmaxf(u.z,u.w)));
    }
    #pragma unroll
    for (int m = 1; m < 8; m <<= 1){
      vmin = fminf(vmin, __shfl_xor(vmin, m));
      vmax = fmaxf(vmax, __shfl_xor(vmax, m));
    }
    const float sc = PI_HALF / (vmax - vmin + 1e-6f);
    #pragma unroll
    for (int j = 0; j < 32; ++j){
      float a = (xv[j] - vmin) * sc;
      phiT[(c0 + j)*36 + row] = pack2h(__cosf(a), __sinf(a));
    }
  }
  __syncthreads();

  // ---- Phase 2: left_1 = c(0)*first0 + s(0)*first1 -> A frags (buf 1, kt=w) ----
  {
    float f0[8], f1[8];
    #pragma unroll
    for (int j = 0; j < 8; ++j){
      int l = 32*w + 8*q + j;
      f0[j] = first[l];
      f1[j] = first[128 + l];
    }
    #pragma unroll
    for (int mt = 0; mt < 2; ++mt){
      h2 ph0 = __builtin_bit_cast(h2, phiT[0*36 + 16*mt + r]);   // row m = 16mt+r
      const float c0 = (float)ph0[0], s0 = (float)ph0[1];
      uint4 o;
      o.x = pack2h(f0[0]*c0 + f1[0]*s0, f0[1]*c0 + f1[1]*s0);
      o.y = pack2h(f0[2]*c0 + f1[2]*s0, f0[3]*c0 + f1[3]*s0);
      o.z = pack2h(f0[4]*c0 + f1[4]*s0, f0[5]*c0 + f1[5]*s0);
      o.w = pack2h(f0[6]*c0 + f1[6]*s0, f0[7]*c0 + f1[7]*s0);
      *(uint4*)&AfragU[2048 + ((mt*4 + w)*64 + physL)*4] = o;
    }
  }

  // ---- B prefetch for body(1) (mid index 0) ----
  uint4 Breg0[16], Breg1[16];   // [d*8 + kt*2 + nb]
  {
    const uint4* bp = (const uint4*)wsB;
    #pragma unroll
    for (int d = 0; d < 2; ++d)
      #pragma unroll
      for (int kt = 0; kt < 4; ++kt)
        #pragma unroll
        for (int nb = 0; nb < 2; ++nb)
          Breg0[d*8+kt*2+nb] = bp[(size_t)((d*4 + kt)*8 + 2*w + nb)*64 + lane];
  }

  // ---- Site body (one barrier per site) ----
  auto body = [&](int site, uint4 (&Bcur)[16], uint4 (&Bnxt)[16]){
    __syncthreads();   // A frags for `site` visible; prev-buf reads done

    // prefetch B for site+1 (mid index `site`; clamped, unused at 254)
    {
      const int soff = (site <= 253) ? site : 0;
      const uint4* bp = (const uint4*)wsB + (size_t)soff * SITE_U4;
      #pragma unroll
      for (int d = 0; d < 2; ++d)
        #pragma unroll
        for (int kt = 0; kt < 4; ++kt)
          #pragma unroll
          for (int nb = 0; nb < 2; ++nb)
            Bnxt[d*8+kt*2+nb] = bp[(size_t)((d*4 + kt)*8 + 2*w + nb)*64 + lane];
    }

    // MFMA: P0 = left @ M0, P1 = left @ M1 over this wave's 32-col strip.
    // acc row = 16mt+4q+reg, col l = 16(2w+nb)+r.
    v4f acc0[2][2] = {};
    v4f acc1[2][2] = {};
    const unsigned* Abuf = &AfragU[(site & 1) * 2048];
    #pragma unroll
    for (int kt = 0; kt < 4; ++kt){
      uint4 a0 = *(const uint4*)&Abuf[((0*4 + kt)*64 + physL)*4];
      uint4 a1 = *(const uint4*)&Abuf[((1*4 + kt)*64 + physL)*4];
      acc0[0][0] = mfma16h(a0, Bcur[0 + kt*2 + 0], acc0[0][0]);
      acc0[0][1] = mfma16h(a0, Bcur[0 + kt*2 + 1], acc0[0][1]);
      acc1[0][0] = mfma16h(a0, Bcur[8 + kt*2 + 0], acc1[0][0]);
      acc1[0][1] = mfma16h(a0, Bcur[8 + kt*2 + 1], acc1[0][1]);
      acc0[1][0] = mfma16h(a1, Bcur[0 + kt*2 + 0], acc0[1][0]);
      acc0[1][1] = mfma16h(a1, Bcur[0 + kt*2 + 1], acc0[1][1]);
      acc1[1][0] = mfma16h(a1, Bcur[8 + kt*2 + 0], acc1[1][0]);
      acc1[1][1] = mfma16h(a1, Bcur[8 + kt*2 + 1], acc1[1][1]);
    }

    if (site < 254){
      // epilogue: left'[m][l] = c_m(site)*P0 + s_m(site)*P1, b16 scatter into
      // next A buf at swizzled slot. Dest slot S = 32nb+16rh+4q+reg (kt = w).
      unsigned short* Wb = (unsigned short*)&AfragU[((site+1) & 1) * 2048];
      #pragma unroll
      for (int mt = 0; mt < 2; ++mt){
        uint4 phiu = *(const uint4*)&phiT[site*36 + 16*mt + 4*q];
        const unsigned pr[4] = {phiu.x, phiu.y, phiu.z, phiu.w};
        const int base16 = (mt*4 + w)*512;
        #pragma unroll
        for (int nb = 0; nb < 2; ++nb){
          const int S0 = 32*nb + 16*rh + 4*q;
          const int X  = 4*nb + 2*rh + (q >> 1);
          #pragma unroll
          for (int reg = 0; reg < 4; ++reg){
            h2 ph = __builtin_bit_cast(h2, pr[reg]);
            float v = (float)ph[0]*acc0[mt][nb][reg]
                    + (float)ph[1]*acc1[mt][nb][reg];
            const int phys = (S0 + reg) ^ X;
            Wb[base16 + phys*8 + wtail] =
                __builtin_bit_cast(unsigned short, (_Float16)v);
          }
        }
      }
    } else {
      // final: left255 = c(254)*P0 + s(254)*P1;
      // scalar[m] = c255_m * sum_l left255*last[l][0] + s255_m * sum_l left255*last[l][1]
      float pA[2][4] = {};
      float pB[2][4] = {};
      #pragma unroll
      for (int mt = 0; mt < 2; ++mt){
        uint4 p4 = *(const uint4*)&phiT[254*36 + 16*mt + 4*q];
        const unsigned pr4[4] = {p4.x, p4.y, p4.z, p4.w};
        #pragma unroll
        for (int nb = 0; nb < 2; ++nb){
          const int l = 16*(2*w + nb) + r;
          float2 gg = *(const float2*)(lastw + 2*l);
          #pragma unroll
          for (int reg = 0; reg < 4; ++reg){
            h2 ph = __builtin_bit_cast(h2, pr4[reg]);
            float v = (float)ph[0]*acc0[mt][nb][reg]
                    + (float)ph[1]*acc1[mt][nb][reg];
            pA[mt][reg] += v * gg.x;
            pB[mt][reg] += v * gg.y;
          }
        }
      }
      float part[2][4];
      #pragma unroll
      for (int mt = 0; mt < 2; ++mt){
        uint4 p5 = *(const uint4*)&phiT[255*36 + 16*mt + 4*q];
        const unsigned pr5[4] = {p5.x, p5.y, p5.z, p5.w};
        #pragma unroll
        for (int reg = 0; reg < 4; ++reg){
          h2 ph = __builtin_bit_cast(h2, pr5[reg]);
          part[mt][reg] = (float)ph[0]*pA[mt][reg] + (float)ph[1]*pB[mt][reg];
        }
      }
      #pragma unroll
      for (int m = 1; m < 16; m <<= 1)
        #pragma unroll
        for (int mt = 0; mt < 2; ++mt)
          #pragma unroll
          for (int reg = 0; reg < 4; ++reg)
            part[mt][reg] += __shfl_xor(part[mt][reg], m);
      if (tid < 32) scal[tid] = 0.0f;
      __syncthreads();
      if (r == 0){
        #pragma unroll
        for (int mt = 0; mt < 2; ++mt)
          #pragma unroll
          for (int reg = 0; reg < 4; ++reg)
            atomicAdd(&scal[16*mt + 4*q + reg], part[mt][reg]);
      }
      __syncthreads();
      for (int t = tid; t < 320; t += 256){
        int bb = t / 10, o = t - bb*10;
        out[(size_t)(rowbase + bb)*10 + o] = scal[bb]*wlin[o] + blin[o];
      }
    }
  };

  #pragma unroll 1
  for (int i = 1; i <= 253; i += 2){
    body(i,     Breg0, Breg1);
    body(i + 1, Breg1, Breg0);
  }
}

extern "C" void kernel_launch(void* const* d_in, const int* in_sizes, int n_in,
                              void* d_out, int out_size, void* d_ws, size_t ws_size,
                              hipStream_t stream){
  (void)in_sizes; (void)n_in; (void)out_size; (void)ws_size;
  const float* x     = (const float*)d_in[0];
  const float* first = (const float*)d_in[1];
  const float* mid   = (const float*)d_in[2];
  const float* lastw = (const float*)d_in[3];
  const float* wlin  = (const float*)d_in[4];
  const float* blin  = (const float*)d_in[5];
  float* o            = (float*)d_out;
  unsigned short* wsB = (unsigned short*)d_ws;   // 16.6 MB fp16 fragments

  hipLaunchKernelGGL(repack_mid, dim3(1016), dim3(256), 0, stream, mid, wsB);
  hipLaunchKernelGGL(mps_main,   dim3(256),  dim3(256), 0, stream,
                     x, first, wsB, lastw, wlin, blin, o);
}

// Round 2
// 285.330 us; speedup vs baseline: 1.1537x; 1.1537x over previous
//
#include <hip/hip_runtime.h>

// MPS classifier, MI355X gfx950. Round 8: 8-wave WGs (2 waves/SIMD) for TLP.
// r7 post-mortem: dur pinned at 273us across structurally different kernels ->
// latency-bound at 1 wave/SIMD (~1900 stall cyc/site), not VALU/LDS-bound.
// Fix: 512-thread WGs, wave g owns a 16-col strip (ntg=g) of BOTH d-planes.
// Per-wave B: 8 uint4/site (was 16), WG B traffic unchanged (64 KB/site),
// A-frag LDS layout unchanged, 2 waves/SIMD overlap L2 latency + barrier drain.
// Split-phi recurrence per site: left' = c_b*(left @ M0) + s_b*(left @ M1).
// B=8192, N=256, D=128, OUT=10. 256 WGs x 512 threads, 32 batch rows/WG.

typedef _Float16 v8h __attribute__((ext_vector_type(8)));
typedef _Float16 h2  __attribute__((ext_vector_type(2)));
typedef float    v4f __attribute__((ext_vector_type(4)));

#define PI_HALF 1.5707963267948966f
#define SITE_U4 4096   // uint4 per site in wsB: 2 d-planes * 4 kt * 8 ntg * 64 lanes

union U4H8 { uint4 u; v8h h; };

__device__ __forceinline__ v4f mfma16h(uint4 a, uint4 b, v4f c){
  U4H8 ua, ub; ua.u = a; ub.u = b;
  return __builtin_amdgcn_mfma_f32_16x16x32_f16(ua.h, ub.h, c, 0, 0, 0);
}
__device__ __forceinline__ unsigned pack2h(float lo, float hi){
  h2 p; p[0] = (_Float16)lo; p[1] = (_Float16)hi;
  return __builtin_bit_cast(unsigned, p);
}

// ---------------------------------------------------------------------------
// Repack mid (fp32 [254][128][2][128]) -> two fp16 B-matrices per site:
// wsB[site][d][kt(4)][ntg(8)][lane(64)] uint4: element (lane, j) =
//   mid[site][k = 32kt+8(lane>>4)+j][d][n = 16ntg+(lane&15)]   (j = 0..7)
// ---------------------------------------------------------------------------
__global__ __launch_bounds__(256) void repack_mid(const float* __restrict__ mid,
                                                  unsigned short* __restrict__ wsB){
  int idx  = blockIdx.x * 256 + threadIdx.x;   // 254*2*4*8*16 = 260096 threads
  int lg   = idx & 15;
  int nt   = (idx >> 4) & 7;
  int kt   = (idx >> 7) & 3;
  int d    = (idx >> 9) & 1;
  int site = idx >> 10;
  int q    = lg >> 2;
  int n0   = 16*nt + 4*(lg & 3);
  // src: mid[site][32kt+8q+j][d][n0..n0+3]; j-stride = 2*128 floats
  const float* src = mid + ((size_t)(site*128 + 32*kt + 8*q)*2 + d)*128 + n0;
  float V[8][4];
  #pragma unroll
  for (int j = 0; j < 8; ++j){
    float4 a = *(const float4*)(src + (size_t)j*256);
    V[j][0]=a.x; V[j][1]=a.y; V[j][2]=a.z; V[j][3]=a.w;
  }
  uint4* dst = (uint4*)wsB + ((((size_t)site*2 + d)*4 + kt)*8 + nt)*64
             + 16*q + 4*(lg & 3);
  #pragma unroll
  for (int t = 0; t < 4; ++t){
    uint4 o;
    o.x = pack2h(V[0][t], V[1][t]);
    o.y = pack2h(V[2][t], V[3][t]);
    o.z = pack2h(V[4][t], V[5][t]);
    o.w = pack2h(V[6][t], V[7][t]);
    dst[t] = o;
  }
}

// ---------------------------------------------------------------------------
// Main persistent kernel. LDS: phiT[256][36] packed f16 (cos,sin), 36 KB;
// AfragU 2 bufs x 8 KB (K=128 A-frags, XOR-swizzled slots); scal[32].
// A-frag logical layout: slot L of (mt,kt) holds A[16mt+(L&15)][32kt+8(L>>4)+j],
// stored at phys slot L ^ ((L>>3)&7).
// Wave g (0..7): cols [16g, 16g+16) of both plane products.
// ---------------------------------------------------------------------------
__global__ __launch_bounds__(512, 2) void mps_main(
    const float* __restrict__ x,               // [8192][256]
    const float* __restrict__ first,           // [2][128]
    const unsigned short* __restrict__ wsB,    // repacked mid, fp16 frags
    const float* __restrict__ lastw,           // [128][2]
    const float* __restrict__ wlin,            // [10]
    const float* __restrict__ blin,            // [10]
    float* __restrict__ out)                   // [8192][10]
{
  __shared__ unsigned phiT[256*36];
  __shared__ unsigned AfragU[2*2*4*64*4];      // [buf][mt][kt][slot][word], 16 KB
  __shared__ float scal[32];

  const int tid  = threadIdx.x;
  const int g    = blockIdx.x;
  const int w    = tid >> 6;             // wave 0..7: cols [16w, 16w+16)
  const int lane = tid & 63;
  const int r    = lane & 15;
  const int q    = lane >> 4;
  const int rowbase = g * 32;
  const int physL = lane ^ ((lane >> 3) & 7);        // swizzled own-slot
  const int rh    = r >> 3;

  // ---- Phase 1: feature map -> packed f16 (cos,sin) table ----
  {
    const int row = tid >> 4;            // 0..31
    const int c0  = (tid & 15) * 16;     // 16-site chunk
    const float4* xp = (const float4*)(x + (size_t)(rowbase + row) * 256 + c0);
    float xv[16];
    float vmin = 3.0e38f, vmax = -3.0e38f;
    #pragma unroll
    for (int c = 0; c < 4; ++c){
      float4 u = xp[c];
      xv[c*4+0] = u.x; xv[c*4+1] = u.y; xv[c*4+2] = u.z; xv[c*4+3] = u.w;
      vmin = fminf(vmin, fminf(fminf(u.x,u.y), fminf(u.z,u.w)));
      vmax = fmaxf(vmax, fmaxf(fmaxf(u.x,u.y), fmaxf(u.z,u.w)));
    }
    #pragma unroll
    for (int m = 1; m < 16; m <<= 1){
      vmin = fminf(vmin, __shfl_xor(vmin, m));
      vmax = fmaxf(vmax, __shfl_xor(vmax, m));
    }
    const float sc = PI_HALF / (vmax - vmin + 1e-6f);
    #pragma unroll
    for (int j = 0; j < 16; ++j){
      float a = (xv[j] - vmin) * sc;
      phiT[(c0 + j)*36 + row] = pack2h(__cosf(a), __sinf(a));
    }
  }
  __syncthreads();

  // ---- Phase 2: left_1 = c(0)*first0 + s(0)*first1 -> A frags (buf 1) ----
  // Wave w writes frag (mt = w>>2, kt = w&3): 64 slots x 16B.
  {
    const int mt = w >> 2, kt = w & 3;
    float f0[8], f1[8];
    #pragma unroll
    for (int j = 0; j < 8; ++j){
      int l = 32*kt + 8*q + j;
      f0[j] = first[l];
      f1[j] = first[128 + l];
    }
    h2 ph0 = __builtin_bit_cast(h2, phiT[0*36 + 16*mt + r]);   // row m = 16mt+r
    const float c0 = (float)ph0[0], s0 = (float)ph0[1];
    uint4 o;
    o.x = pack2h(f0[0]*c0 + f1[0]*s0, f0[1]*c0 + f1[1]*s0);
    o.y = pack2h(f0[2]*c0 + f1[2]*s0, f0[3]*c0 + f1[3]*s0);
    o.z = pack2h(f0[4]*c0 + f1[4]*s0, f0[5]*c0 + f1[5]*s0);
    o.w = pack2h(f0[6]*c0 + f1[6]*s0, f0[7]*c0 + f1[7]*s0);
    *(uint4*)&AfragU[2048 + ((mt*4 + kt)*64 + physL)*4] = o;
  }

  // ---- B prefetch for body(1) (mid index 0): wave w's 16-col strip ----
  uint4 Breg0[8], Breg1[8];   // [d*4 + kt]
  {
    const uint4* bp = (const uint4*)wsB;
    #pragma unroll
    for (int d = 0; d < 2; ++d)
      #pragma unroll
      for (int kt = 0; kt < 4; ++kt)
        Breg0[d*4+kt] = bp[(size_t)((d*4 + kt)*8 + w)*64 + lane];
  }

  // ---- Site body (one barrier per site) ----
  auto body = [&](int site, uint4 (&Bcur)[8], uint4 (&Bnxt)[8]){
    __syncthreads();   // A frags for `site` visible; prev-buf reads done

    // prefetch B for site+1 (mid index `site`; clamped, unused at 254)
    {
      const int soff = (site <= 253) ? site : 0;
      const uint4* bp = (const uint4*)wsB + (size_t)soff * SITE_U4;
      #pragma unroll
      for (int d = 0; d < 2; ++d)
        #pragma unroll
        for (int kt = 0; kt < 4; ++kt)
          Bnxt[d*4+kt] = bp[(size_t)((d*4 + kt)*8 + w)*64 + lane];
    }

    // MFMA: P0 = left @ M0, P1 = left @ M1 over this wave's 16-col strip.
    // acc row = 16mt+4q+reg, col l = 16w+r.
    v4f acc0[2] = {};   // plane 0, [mt]
    v4f acc1[2] = {};   // plane 1, [mt]
    const unsigned* Abuf = &AfragU[(site & 1) * 2048];
    #pragma unroll
    for (int kt = 0; kt < 4; ++kt){
      uint4 a0 = *(const uint4*)&Abuf[((0*4 + kt)*64 + physL)*4];
      uint4 a1 = *(const uint4*)&Abuf[((1*4 + kt)*64 + physL)*4];
      acc0[0] = mfma16h(a0, Bcur[0 + kt], acc0[0]);
      acc0[1] = mfma16h(a1, Bcur[0 + kt], acc0[1]);
      acc1[0] = mfma16h(a0, Bcur[4 + kt], acc1[0]);
      acc1[1] = mfma16h(a1, Bcur[4 + kt], acc1[1]);
    }

    if (site < 254){
      // epilogue: left'[m][l] = c_m(site)*P0 + s_m(site)*P1, b16 scatter into
      // next A buf at swizzled slot. col l = 16w+r -> kt = w>>1,
      // slot S = 32(w&1)+16rh+4q+reg, X = 4(w&1)+2rh+(q>>1), j = r&7.
      unsigned short* Wb = (unsigned short*)&AfragU[((site+1) & 1) * 2048];
      const int X = 4*(w & 1) + 2*rh + (q >> 1);
      const int S0 = 32*(w & 1) + 16*rh + 4*q;
      #pragma unroll
      for (int mt = 0; mt < 2; ++mt){
        uint4 phiu = *(const uint4*)&phiT[site*36 + 16*mt + 4*q];
        const unsigned pr[4] = {phiu.x, phiu.y, phiu.z, phiu.w};
        const int base16 = (mt*4 + (w >> 1))*512;
        #pragma unroll
        for (int reg = 0; reg < 4; ++reg){
          h2 ph = __builtin_bit_cast(h2, pr[reg]);
          float v = (float)ph[0]*acc0[mt][reg]
                  + (float)ph[1]*acc1[mt][reg];
          const int phys = (S0 + reg) ^ X;
          Wb[base16 + phys*8 + (r & 7)] =
              __builtin_bit_cast(unsigned short, (_Float16)v);
        }
      }
    } else {
      // final: left255 = c(254)*P0 + s(254)*P1;
      // scalar[m] = c255_m * sum_l left255*last[l][0] + s255_m * sum_l ...[l][1]
      float pA[2][4] = {};
      float pB[2][4] = {};
      const int l = 16*w + r;
      float2 gg = *(const float2*)(lastw + 2*l);
      #pragma unroll
      for (int mt = 0; mt < 2; ++mt){
        uint4 p4 = *(const uint4*)&phiT[254*36 + 16*mt + 4*q];
        const unsigned pr4[4] = {p4.x, p4.y, p4.z, p4.w};
        #pragma unroll
        for (int reg = 0; reg < 4; ++reg){
          h2 ph = __builtin_bit_cast(h2, pr4[reg]);
          float v = (float)ph[0]*acc0[mt][reg]
                  + (float)ph[1]*acc1[mt][reg];
          pA[mt][reg] += v * gg.x;
          pB[mt][reg] += v * gg.y;
        }
      }
      float part[2][4];
      #pragma unroll
      for (int mt = 0; mt < 2; ++mt){
        uint4 p5 = *(const uint4*)&phiT[255*36 + 16*mt + 4*q];
        const unsigned pr5[4] = {p5.x, p5.y, p5.z, p5.w};
        #pragma unroll
        for (int reg = 0; reg < 4; ++reg){
          h2 ph = __builtin_bit_cast(h2, pr5[reg]);
          part[mt][reg] = (float)ph[0]*pA[mt][reg] + (float)ph[1]*pB[mt][reg];
        }
      }
      #pragma unroll
      for (int m = 1; m < 16; m <<= 1)
        #pragma unroll
        for (int mt = 0; mt < 2; ++mt)
          #pragma unroll
          for (int reg = 0; reg < 4; ++reg)
            part[mt][reg] += __shfl_xor(part[mt][reg], m);
      if (tid < 32) scal[tid] = 0.0f;
      __syncthreads();
      if (r == 0){
        #pragma unroll
        for (int mt = 0; mt < 2; ++mt)
          #pragma unroll
          for (int reg = 0; reg < 4; ++reg)
            atomicAdd(&scal[16*mt + 4*q + reg], part[mt][reg]);
      }
      __syncthreads();
      for (int t = tid; t < 320; t += 512){
        int bb = t / 10, o = t - bb*10;
        out[(size_t)(rowbase + bb)*10 + o] = scal[bb]*wlin[o] + blin[o];
      }
    }
  };

  #pragma unroll 1
  for (int i = 1; i <= 253; i += 2){
    body(i,     Breg0, Breg1);
    body(i + 1, Breg1, Breg0);
  }
}

extern "C" void kernel_launch(void* const* d_in, const int* in_sizes, int n_in,
                              void* d_out, int out_size, void* d_ws, size_t ws_size,
                              hipStream_t stream){
  (void)in_sizes; (void)n_in; (void)out_size; (void)ws_size;
  const float* x     = (const float*)d_in[0];
  const float* first = (const float*)d_in[1];
  const float* mid   = (const float*)d_in[2];
  const float* lastw = (const float*)d_in[3];
  const float* wlin  = (const float*)d_in[4];
  const float* blin  = (const float*)d_in[5];
  float* o            = (float*)d_out;
  unsigned short* wsB = (unsigned short*)d_ws;   // 16.6 MB fp16 fragments

  hipLaunchKernelGGL(repack_mid, dim3(1016), dim3(256), 0, stream, mid, wsB);
  hipLaunchKernelGGL(mps_main,   dim3(256),  dim3(512), 0, stream,
                     x, first, wsB, lastw, wlin, blin, o);
}

// Round 3
// 269.666 us; speedup vs baseline: 1.2207x; 1.0581x over previous
//
#include <hip/hip_runtime.h>

// MPS classifier, MI355X gfx950. Round 9: bidirectional contraction.
// Waves 0-3: forward  left' = c_b*(left @ M0) + s_b*(left @ M1)   (state = A-op in LDS)
// Waves 4-7: backward R'    = c_b*(M0 @ R)    + s_b*(M1 @ R)      (state = B-op in LDS)
// meet in the middle: scalar[b] = sum_l L128[b,l] * R127[l,b].
// Per step (2 sites): each b128 A/R-state read feeds 4 MFMAs (LDS reads/site
// halved vs r8), one barrier per TWO sites (127 total), and each SIMD carries
// one fwd + one bwd wave with independent chains (true latency overlap).
// wsB: fwd B-op frags (16.6 MB) + bwd A-op transposed frags (16.6 MB) = 33.3 MB.
// B=8192, N=256, D=128, OUT=10. 256 WGs x 512 threads, 32 batch rows/WG.

typedef _Float16 v8h __attribute__((ext_vector_type(8)));
typedef _Float16 h2  __attribute__((ext_vector_type(2)));
typedef float    v4f __attribute__((ext_vector_type(4)));

#define PI_HALF 1.5707963267948966f
#define SITE_U4 4096                 // uint4 per site per half: 2d * 32 regions * 64
#define TOFF_U4 (254*4096)           // bwd (transposed) half base, in uint4

union U4H8 { uint4 u; v8h h; };

__device__ __forceinline__ v4f mfma16h(uint4 a, uint4 b, v4f c){
  U4H8 ua, ub; ua.u = a; ub.u = b;
  return __builtin_amdgcn_mfma_f32_16x16x32_f16(ua.h, ub.h, c, 0, 0, 0);
}
__device__ __forceinline__ unsigned pack2h(float lo, float hi){
  h2 p; p[0] = (_Float16)lo; p[1] = (_Float16)hi;
  return __builtin_bit_cast(unsigned, p);
}

// ---------------------------------------------------------------------------
// Repack mid (fp32 [254][128][2][128]).
// Blocks 0..1015  -> fwd B-op frags: wsB[site][d][kt(4)][nt(8)][64] uint4,
//   element (lane,j) = mid[site][k=32kt+8(lane>>4)+j][d][n=16nt+(lane&15)]
// Blocks 1016..2031 -> bwd A-op frags (transposed): at TOFF_U4,
//   [site][d][am(8)][kt(4)][64]: element (lane,j) =
//   mid[site][m=16am+(lane&15)][d][k=32kt+8(lane>>4)+j]
// ---------------------------------------------------------------------------
__global__ __launch_bounds__(256) void repack_mid(const float* __restrict__ mid,
                                                  unsigned short* __restrict__ wsB){
  const int bid = blockIdx.x;
  if (bid < 1016){
    int idx  = bid * 256 + threadIdx.x;
    int lg   = idx & 15;
    int nt   = (idx >> 4) & 7;
    int kt   = (idx >> 7) & 3;
    int d    = (idx >> 9) & 1;
    int site = idx >> 10;
    int q    = lg >> 2;
    int n0   = 16*nt + 4*(lg & 3);
    const float* src = mid + ((size_t)(site*128 + 32*kt + 8*q)*2 + d)*128 + n0;
    float V[8][4];
    #pragma unroll
    for (int j = 0; j < 8; ++j){
      float4 a = *(const float4*)(src + (size_t)j*256);
      V[j][0]=a.x; V[j][1]=a.y; V[j][2]=a.z; V[j][3]=a.w;
    }
    uint4* dst = (uint4*)wsB + ((((size_t)site*2 + d)*4 + kt)*8 + nt)*64
               + 16*q + 4*(lg & 3);
    #pragma unroll
    for (int t = 0; t < 4; ++t){
      uint4 o;
      o.x = pack2h(V[0][t], V[1][t]);
      o.y = pack2h(V[2][t], V[3][t]);
      o.z = pack2h(V[4][t], V[5][t]);
      o.w = pack2h(V[6][t], V[7][t]);
      dst[t] = o;
    }
  } else {
    int idx  = (bid - 1016) * 256 + threadIdx.x;
    int lg   = idx & 15;
    int kt   = (idx >> 4) & 3;
    int am   = (idx >> 6) & 7;
    int d    = (idx >> 9) & 1;
    int site = idx >> 10;
    int q    = lg >> 2;
    int m0   = 16*am + 4*(lg & 3);
    int k0   = 32*kt + 8*q;
    uint4* dst = (uint4*)wsB + TOFF_U4
               + ((((size_t)site*2 + d)*8 + am)*4 + kt)*64 + 16*q + 4*(lg & 3);
    #pragma unroll
    for (int mp = 0; mp < 4; ++mp){
      const float* src = mid + ((size_t)((site*128 + m0 + mp)*2) + d)*128 + k0;
      float4 a = *(const float4*)(src);
      float4 b = *(const float4*)(src + 4);
      uint4 o;
      o.x = pack2h(a.x, a.y);
      o.y = pack2h(a.z, a.w);
      o.z = pack2h(b.x, b.y);
      o.w = pack2h(b.z, b.w);
      dst[mp] = o;
    }
  }
}

// ---------------------------------------------------------------------------
// Main kernel. LDS: phiT[256][36] packed f16 (cos,sin); Af (fwd state A-op
// frags) 2 bufs x 8 KB; Rf (bwd state B-op frags) 2 bufs x 8 KB;
// Rcomb[128][33] f32 for the middle combine; scal[32].
// Swizzle: logical slot S stored at phys = S ^ ((S>>3)&7); reads use
// physL = lane ^ ((lane>>3)&7).
// ---------------------------------------------------------------------------
__global__ __launch_bounds__(512, 2) void mps_main(
    const float* __restrict__ x,               // [8192][256]
    const float* __restrict__ first,           // [2][128]
    const unsigned short* __restrict__ wsBv,   // repacked mid (both halves)
    const float* __restrict__ lastw,           // [128][2]
    const float* __restrict__ wlin,            // [10]
    const float* __restrict__ blin,            // [10]
    float* __restrict__ out)                   // [8192][10]
{
  __shared__ unsigned phiT[256*36];        // 36 KB
  __shared__ unsigned Af[2*2*4*64*4];      // 16 KB  [buf][mt][kt][slot][word]
  __shared__ unsigned Rf[2*4*2*64*4];      // 16 KB  [buf][kt][nt][slot][word]
  __shared__ float Rcomb[128*33];          // 16.9 KB
  __shared__ float scal[32];

  const int tid  = threadIdx.x;
  const int gblk = blockIdx.x;
  const int w    = tid >> 6;               // 0..3 fwd, 4..7 bwd
  const int lane = tid & 63;
  const int r    = lane & 15;
  const int q    = lane >> 4;
  const int rh   = r >> 3;
  const int rowbase = gblk * 32;
  const int physL = lane ^ ((lane >> 3) & 7);

  // ---- Phase 1: feature map -> packed f16 (cos,sin) table ----
  {
    const int row = tid >> 4;              // 0..31
    const int c0  = (tid & 15) * 16;       // 16-site chunk
    const float4* xp = (const float4*)(x + (size_t)(rowbase + row) * 256 + c0);
    float xv[16];
    float vmin = 3.0e38f, vmax = -3.0e38f;
    #pragma unroll
    for (int c = 0; c < 4; ++c){
      float4 u = xp[c];
      xv[c*4+0] = u.x; xv[c*4+1] = u.y; xv[c*4+2] = u.z; xv[c*4+3] = u.w;
      vmin = fminf(vmin, fminf(fminf(u.x,u.y), fminf(u.z,u.w)));
      vmax = fmaxf(vmax, fmaxf(fmaxf(u.x,u.y), fmaxf(u.z,u.w)));
    }
    #pragma unroll
    for (int m = 1; m < 16; m <<= 1){
      vmin = fminf(vmin, __shfl_xor(vmin, m));
      vmax = fmaxf(vmax, __shfl_xor(vmax, m));
    }
    const float sc = PI_HALF / (vmax - vmin + 1e-6f);
    #pragma unroll
    for (int j = 0; j < 16; ++j){
      float a = (xv[j] - vmin) * sc;
      phiT[(c0 + j)*36 + row] = pack2h(__cosf(a), __sinf(a));
    }
  }
  __syncthreads();

  // ---- Initial B prefetch (step 0): fwd site 0, bwd site 253 ----
  uint4 B0[16], B1[16];
  if (w < 4){
    const uint4* bp = (const uint4*)wsBv;
    #pragma unroll
    for (int d = 0; d < 2; ++d)
      #pragma unroll
      for (int kt = 0; kt < 4; ++kt)
        #pragma unroll
        for (int nb = 0; nb < 2; ++nb)
          B0[(d*4+kt)*2+nb] = bp[(size_t)((d*4 + kt)*8 + 2*w + nb)*64 + lane];
  } else {
    const int ww = w - 4;
    const uint4* bp = (const uint4*)wsBv + TOFF_U4 + (size_t)253 * SITE_U4;
    #pragma unroll
    for (int d = 0; d < 2; ++d)
      #pragma unroll
      for (int mtl = 0; mtl < 2; ++mtl)
        #pragma unroll
        for (int kt = 0; kt < 4; ++kt)
          B0[(d*2+mtl)*4+kt] = bp[(size_t)((d*8 + 2*ww + mtl)*4 + kt)*64 + lane];
  }

  // ---- State init (buf 0) ----
  if (w < 4){
    // left_1[b][l] = c0(b)*first[0][l] + s0(b)*first[1][l]; wave w: kt=w
    float f0[8], f1[8];
    #pragma unroll
    for (int j = 0; j < 8; ++j){
      int l = 32*w + 8*q + j;
      f0[j] = first[l]; f1[j] = first[128 + l];
    }
    #pragma unroll
    for (int mt = 0; mt < 2; ++mt){
      h2 ph0 = __builtin_bit_cast(h2, phiT[0*36 + 16*mt + r]);
      const float c0 = (float)ph0[0], s0 = (float)ph0[1];
      uint4 o;
      o.x = pack2h(f0[0]*c0 + f1[0]*s0, f0[1]*c0 + f1[1]*s0);
      o.y = pack2h(f0[2]*c0 + f1[2]*s0, f0[3]*c0 + f1[3]*s0);
      o.z = pack2h(f0[4]*c0 + f1[4]*s0, f0[5]*c0 + f1[5]*s0);
      o.w = pack2h(f0[6]*c0 + f1[6]*s0, f0[7]*c0 + f1[7]*s0);
      *(uint4*)&Af[((mt*4 + w)*64 + physL)*4] = o;
    }
  } else {
    // R_end[k][b] = lastw[k][0]*c255(b) + lastw[k][1]*s255(b); wave ww: kt=ww
    const int ww = w - 4;
    float g0[8], g1[8];
    #pragma unroll
    for (int j = 0; j < 8; ++j){
      int rr = 32*ww + 8*q + j;
      float2 gg = *(const float2*)(lastw + 2*rr);
      g0[j] = gg.x; g1[j] = gg.y;
    }
    #pragma unroll
    for (int nt = 0; nt < 2; ++nt){
      h2 p5 = __builtin_bit_cast(h2, phiT[255*36 + 16*nt + r]);
      const float cb = (float)p5[0], sb = (float)p5[1];
      uint4 o;
      o.x = pack2h(g0[0]*cb + g1[0]*sb, g0[1]*cb + g1[1]*sb);
      o.y = pack2h(g0[2]*cb + g1[2]*sb, g0[3]*cb + g1[3]*sb);
      o.z = pack2h(g0[4]*cb + g1[4]*sb, g0[5]*cb + g1[5]*sb);
      o.w = pack2h(g0[6]*cb + g1[6]*sb, g0[7]*cb + g1[7]*sb);
      *(uint4*)&Rf[((ww*2 + nt)*64 + physL)*4] = o;
    }
  }

  // ---- Step body: fwd consumes mid[t], phi(t+1); bwd mid[253-t], phi(254-t) ----
  auto body = [&](int t, uint4 (&Fc)[16], uint4 (&Fn)[16]){
    __syncthreads();   // state frags for step t visible; prev-buf reads done
    float vf[2][2][4]; // fwd final values (only live at t==126)

    if (w < 4){
      // prefetch fwd B for step t+1
      {
        const int soff = (t < 126) ? (t + 1) : 0;
        const uint4* bp = (const uint4*)wsBv + (size_t)soff * SITE_U4;
        #pragma unroll
        for (int d = 0; d < 2; ++d)
          #pragma unroll
          for (int kt = 0; kt < 4; ++kt)
            #pragma unroll
            for (int nb = 0; nb < 2; ++nb)
              Fn[(d*4+kt)*2+nb] = bp[(size_t)((d*4 + kt)*8 + 2*w + nb)*64 + lane];
      }
      v4f ac0[2][2] = {};   // [mt][nb], plane 0
      v4f ac1[2][2] = {};   // plane 1
      const unsigned* Ab = &Af[(t & 1) * 2048];
      #pragma unroll
      for (int kt = 0; kt < 4; ++kt){
        uint4 a0 = *(const uint4*)&Ab[((0*4 + kt)*64 + physL)*4];
        uint4 a1 = *(const uint4*)&Ab[((1*4 + kt)*64 + physL)*4];
        #pragma unroll
        for (int nb = 0; nb < 2; ++nb){
          ac0[0][nb] = mfma16h(a0, Fc[(0*4+kt)*2+nb], ac0[0][nb]);
          ac0[1][nb] = mfma16h(a1, Fc[(0*4+kt)*2+nb], ac0[1][nb]);
          ac1[0][nb] = mfma16h(a0, Fc[(1*4+kt)*2+nb], ac1[0][nb]);
          ac1[1][nb] = mfma16h(a1, Fc[(1*4+kt)*2+nb], ac1[1][nb]);
        }
      }
      if (t < 126){
        // left'[b][l]: b=16mt+4q+reg, l=32w+16nb+r -> Af[(t+1)&1], kt=w
        unsigned short* Wb = (unsigned short*)&Af[((t+1) & 1) * 2048];
        #pragma unroll
        for (int mt = 0; mt < 2; ++mt){
          uint4 phiu = *(const uint4*)&phiT[(t+1)*36 + 16*mt + 4*q];
          const unsigned pr[4] = {phiu.x, phiu.y, phiu.z, phiu.w};
          #pragma unroll
          for (int nb = 0; nb < 2; ++nb){
            const int S0 = 32*nb + 16*rh + 4*q;
            const int X  = 4*nb + 2*rh + (q >> 1);
            #pragma unroll
            for (int reg = 0; reg < 4; ++reg){
              h2 ph = __builtin_bit_cast(h2, pr[reg]);
              float v = (float)ph[0]*ac0[mt][nb][reg]
                      + (float)ph[1]*ac1[mt][nb][reg];
              Wb[((mt*4 + w)*64 + ((S0 + reg) ^ X))*8 + (r & 7)] =
                  __builtin_bit_cast(unsigned short, (_Float16)v);
            }
          }
        }
      } else {
        // final fwd: vf = left_128 (phi(127) applied), held in registers
        #pragma unroll
        for (int mt = 0; mt < 2; ++mt){
          uint4 phiu = *(const uint4*)&phiT[127*36 + 16*mt + 4*q];
          const unsigned pr[4] = {phiu.x, phiu.y, phiu.z, phiu.w};
          #pragma unroll
          for (int nb = 0; nb < 2; ++nb)
            #pragma unroll
            for (int reg = 0; reg < 4; ++reg){
              h2 ph = __builtin_bit_cast(h2, pr[reg]);
              vf[mt][nb][reg] = (float)ph[0]*ac0[mt][nb][reg]
                              + (float)ph[1]*ac1[mt][nb][reg];
            }
        }
      }
    } else {
      const int ww = w - 4;
      // prefetch bwd A (transposed frags) for step t+1
      {
        const int soff = (t < 126) ? (252 - t) : 253;
        const uint4* bp = (const uint4*)wsBv + TOFF_U4 + (size_t)soff * SITE_U4;
        #pragma unroll
        for (int d = 0; d < 2; ++d)
          #pragma unroll
          for (int mtl = 0; mtl < 2; ++mtl)
            #pragma unroll
            for (int kt = 0; kt < 4; ++kt)
              Fn[(d*2+mtl)*4+kt] = bp[(size_t)((d*8 + 2*ww + mtl)*4 + kt)*64 + lane];
      }
      v4f ac0[2][2] = {};   // [mtl][nt], plane 0
      v4f ac1[2][2] = {};   // plane 1
      const unsigned* Rb = &Rf[(t & 1) * 2048];
      #pragma unroll
      for (int kt = 0; kt < 4; ++kt){
        uint4 b0 = *(const uint4*)&Rb[((kt*2 + 0)*64 + physL)*4];
        uint4 b1 = *(const uint4*)&Rb[((kt*2 + 1)*64 + physL)*4];
        #pragma unroll
        for (int mtl = 0; mtl < 2; ++mtl){
          ac0[mtl][0] = mfma16h(Fc[(0*2+mtl)*4+kt], b0, ac0[mtl][0]);
          ac0[mtl][1] = mfma16h(Fc[(0*2+mtl)*4+kt], b1, ac0[mtl][1]);
          ac1[mtl][0] = mfma16h(Fc[(1*2+mtl)*4+kt], b0, ac1[mtl][0]);
          ac1[mtl][1] = mfma16h(Fc[(1*2+mtl)*4+kt], b1, ac1[mtl][1]);
        }
      }
      const int ps = 254 - t;
      if (t < 126){
        // R'[k=l][b]: l=32ww+16mtl+4q+reg, b=16nb+r -> Rf[(t+1)&1], kt=ww
        unsigned short* Wr = (unsigned short*)&Rf[((t+1) & 1) * 2048];
        #pragma unroll
        for (int nb = 0; nb < 2; ++nb){
          h2 ph = __builtin_bit_cast(h2, phiT[ps*36 + 16*nb + r]);
          const float cb = (float)ph[0], sb = (float)ph[1];
          #pragma unroll
          for (int mtl = 0; mtl < 2; ++mtl){
            const int S0 = 32*mtl + 16*(q >> 1) + r;
            const int phys = S0 ^ ((S0 >> 3) & 7);
            #pragma unroll
            for (int reg = 0; reg < 4; ++reg){
              float v = cb*ac0[mtl][nb][reg] + sb*ac1[mtl][nb][reg];
              Wr[((ww*2 + nb)*64 + phys)*8 + ((4*q + reg) & 7)] =
                  __builtin_bit_cast(unsigned short, (_Float16)v);
            }
          }
        }
      } else {
        // final bwd: R_127 -> Rcomb[l][b]
        #pragma unroll
        for (int nb = 0; nb < 2; ++nb){
          h2 ph = __builtin_bit_cast(h2, phiT[ps*36 + 16*nb + r]);
          const float cb = (float)ph[0], sb = (float)ph[1];
          #pragma unroll
          for (int mtl = 0; mtl < 2; ++mtl)
            #pragma unroll
            for (int reg = 0; reg < 4; ++reg){
              float v = cb*ac0[mtl][nb][reg] + sb*ac1[mtl][nb][reg];
              int l = 32*ww + 16*mtl + 4*q + reg;
              Rcomb[l*33 + 16*nb + r] = v;
            }
        }
      }
    }

    if (t == 126){
      if (tid < 32) scal[tid] = 0.0f;
      __syncthreads();   // Rcomb + scal ready
      if (w < 4){
        float p[2][4] = {};
        #pragma unroll
        for (int mt = 0; mt < 2; ++mt)
          #pragma unroll
          for (int nb = 0; nb < 2; ++nb){
            const int l = 32*w + 16*nb + r;
            #pragma unroll
            for (int reg = 0; reg < 4; ++reg)
              p[mt][reg] += vf[mt][nb][reg] * Rcomb[l*33 + 16*mt + 4*q + reg];
          }
        #pragma unroll
        for (int m = 1; m < 16; m <<= 1)
          #pragma unroll
          for (int mt = 0; mt < 2; ++mt)
            #pragma unroll
            for (int reg = 0; reg < 4; ++reg)
              p[mt][reg] += __shfl_xor(p[mt][reg], m);
        if (r == 0){
          #pragma unroll
          for (int mt = 0; mt < 2; ++mt)
            #pragma unroll
            for (int reg = 0; reg < 4; ++reg)
              atomicAdd(&scal[16*mt + 4*q + reg], p[mt][reg]);
        }
      }
      __syncthreads();
      for (int t2 = tid; t2 < 320; t2 += 512){
        int bb = t2 / 10, o = t2 - bb*10;
        out[(size_t)(rowbase + bb)*10 + o] = scal[bb]*wlin[o] + blin[o];
      }
    }
  };

  #pragma unroll 1
  for (int t = 0; t < 126; t += 2){
    body(t,     B0, B1);
    body(t + 1, B1, B0);
  }
  body(126, B0, B1);
}

extern "C" void kernel_launch(void* const* d_in, const int* in_sizes, int n_in,
                              void* d_out, int out_size, void* d_ws, size_t ws_size,
                              hipStream_t stream){
  (void)in_sizes; (void)n_in; (void)out_size; (void)ws_size;
  const float* x     = (const float*)d_in[0];
  const float* first = (const float*)d_in[1];
  const float* mid   = (const float*)d_in[2];
  const float* lastw = (const float*)d_in[3];
  const float* wlin  = (const float*)d_in[4];
  const float* blin  = (const float*)d_in[5];
  float* o            = (float*)d_out;
  unsigned short* wsB = (unsigned short*)d_ws;   // 33.3 MB fp16 fragments

  hipLaunchKernelGGL(repack_mid, dim3(2032), dim3(256), 0, stream, mid, wsB);
  hipLaunchKernelGGL(mps_main,   dim3(256),  dim3(512), 0, stream,
                     x, first, wsB, lastw, wlin, blin, o);
}

// Round 4
// 267.345 us; speedup vs baseline: 1.2313x; 1.0087x over previous
//
#include <hip/hip_runtime.h>

// MPS classifier, MI355X gfx950. Round 10: fwd/bwd WORKGROUP split.
// 128 row-groups x 64 rows. WG g<128: forward (mids 0..126, phis 0..127) ->
// Lout[8192][128]. WG g>=128: backward (mids 253..127, phis 255..128) ->
// RoutT[rg][64][128]. combine kernel: scalar[b] = sum_l L[b,l]*R[l,b].
// Waves own EXCLUSIVE 16-col B strips -> per-CU B traffic HALVES to 8.13 MB
// (the r8/r9 binding resource). Cost: each wave reads the full 16 KB state
// from LDS (16 b128/site) -> LDS pipe ~2600 cyc/site is the new wall.
// LDS padded to 112 KB to force 1 WG/CU. Split-phi recurrence throughout:
// left' = c_b*(left @ M0) + s_b*(left @ M1);  R' = c_b*(M0 @ R) + s_b*(M1 @ R).

typedef _Float16 v8h __attribute__((ext_vector_type(8)));
typedef _Float16 h2  __attribute__((ext_vector_type(2)));
typedef float    v4f __attribute__((ext_vector_type(4)));

#define PI_HALF 1.5707963267948966f
#define SITE_U4 4096                 // uint4 per site: 2 planes * 16 frags * 64
#define TOFF_U4 (127*4096)           // bwd half base (uint4)
#define LOUT_F32 (2*TOFF_U4*4)       // float offset of Lout in ws
#define ROUT_F32 (LOUT_F32 + 8192*128)
#define PHI_S 160                    // phi row stride (u32) — pads LDS to force 1 WG/CU

union U4H8 { uint4 u; v8h h; };

__device__ __forceinline__ v4f mfma16h(uint4 a, uint4 b, v4f c){
  U4H8 ua, ub; ua.u = a; ub.u = b;
  return __builtin_amdgcn_mfma_f32_16x16x32_f16(ua.h, ub.h, c, 0, 0, 0);
}
__device__ __forceinline__ unsigned pack2h(float lo, float hi){
  h2 p; p[0] = (_Float16)lo; p[1] = (_Float16)hi;
  return __builtin_bit_cast(unsigned, p);
}
__device__ __forceinline__ unsigned short f16b(float v){
  return __builtin_bit_cast(unsigned short, (_Float16)v);
}

// ---------------------------------------------------------------------------
// Repack mid (fp32 [254][128][2][128]).
// Blocks 0..507   (sites 0..126)  -> fwd B-op frags [site][d][kt4][nt8][64]:
//   (lane,j) = mid[site][k=32kt+8(lane>>4)+j][d][n=16nt+(lane&15)]
// Blocks 508..1015 (sites 127..253)-> bwd A-op frags at TOFF [srel][d][mt8][kt4][64]:
//   (lane,j) = mid[site][m=16mt+(lane&15)][d][k=32kt+8(lane>>4)+j]
// ---------------------------------------------------------------------------
__global__ __launch_bounds__(256) void repack_mid(const float* __restrict__ mid,
                                                  unsigned short* __restrict__ wsB){
  const int bid = blockIdx.x;
  if (bid < 508){
    int idx  = bid * 256 + threadIdx.x;
    int lg   = idx & 15;
    int nt   = (idx >> 4) & 7;
    int kt   = (idx >> 7) & 3;
    int d    = (idx >> 9) & 1;
    int site = idx >> 10;            // 0..126
    int q    = lg >> 2;
    int n0   = 16*nt + 4*(lg & 3);
    const float* src = mid + ((size_t)(site*128 + 32*kt + 8*q)*2 + d)*128 + n0;
    float V[8][4];
    #pragma unroll
    for (int j = 0; j < 8; ++j){
      float4 a = *(const float4*)(src + (size_t)j*256);
      V[j][0]=a.x; V[j][1]=a.y; V[j][2]=a.z; V[j][3]=a.w;
    }
    uint4* dst = (uint4*)wsB + ((((size_t)site*2 + d)*4 + kt)*8 + nt)*64
               + 16*q + 4*(lg & 3);
    #pragma unroll
    for (int t = 0; t < 4; ++t){
      uint4 o;
      o.x = pack2h(V[0][t], V[1][t]);
      o.y = pack2h(V[2][t], V[3][t]);
      o.z = pack2h(V[4][t], V[5][t]);
      o.w = pack2h(V[6][t], V[7][t]);
      dst[t] = o;
    }
  } else {
    int idx  = (bid - 508) * 256 + threadIdx.x;
    int lg   = idx & 15;
    int kt   = (idx >> 4) & 3;
    int am   = (idx >> 6) & 7;
    int d    = (idx >> 9) & 1;
    int srel = idx >> 10;            // 0..126
    int site = 127 + srel;
    int q    = lg >> 2;
    int m0   = 16*am + 4*(lg & 3);
    int k0   = 32*kt + 8*q;
    uint4* dst = (uint4*)wsB + TOFF_U4
               + ((((size_t)srel*2 + d)*8 + am)*4 + kt)*64 + 16*q + 4*(lg & 3);
    #pragma unroll
    for (int mp = 0; mp < 4; ++mp){
      const float* src = mid + ((size_t)((site*128 + m0 + mp)*2) + d)*128 + k0;
      float4 a = *(const float4*)(src);
      float4 b = *(const float4*)(src + 4);
      uint4 o;
      o.x = pack2h(a.x, a.y);
      o.y = pack2h(a.z, a.w);
      o.z = pack2h(b.x, b.y);
      o.w = pack2h(b.z, b.w);
      dst[mp] = o;
    }
  }
}

// ---------------------------------------------------------------------------
// Main kernel: dir = bid>>7 (0 fwd, 1 bwd), rg = bid&127 (rows 64*rg..+64).
// LDS: phiL[128][PHI_S] u32 packed (cos,sin) f16 — fwd sites 0..127, bwd 128..255;
//      Ast 2 bufs x 16 KB state frags (fwd: A-op L[64b x 128k];
//      bwd: B-op R[128k x 64b]). Slot swizzle: phys = S ^ ((S>>3)&7).
// ---------------------------------------------------------------------------
__global__ __launch_bounds__(512, 2) void mps_main(
    const float* __restrict__ x,               // [8192][256]
    const float* __restrict__ first,           // [2][128]
    const unsigned short* __restrict__ wsBv,   // repacked frags + Lout/Rout
    const float* __restrict__ lastw,           // [128][2]
    float* __restrict__ ws_out)                // float view of workspace
{
  __shared__ unsigned phiL[128*PHI_S];        // 80 KB (stride-padded)
  __shared__ unsigned Ast[2*16*64*4];         // 32 KB

  const int tid  = threadIdx.x;
  const int bid  = blockIdx.x;
  const int dir  = bid >> 7;
  const int rg   = bid & 127;
  const int w    = tid >> 6;             // wave 0..7: exclusive 16-wide strip
  const int lane = tid & 63;
  const int r    = lane & 15;
  const int q    = lane >> 4;
  const int rh   = r >> 3;
  const int rowbase = rg * 64;
  const int physL = lane ^ ((lane >> 3) & 7);

  // ---- Phase 1: feature map (min/max over ALL 256 cols) -> this dir's 128 phis ----
  {
    const int row = tid >> 3;            // 0..63
    const int c   = tid & 7;             // 32-col chunk
    const float4* xp = (const float4*)(x + (size_t)(rowbase + row) * 256 + c*32);
    float xv[32];
    float vmin = 3.0e38f, vmax = -3.0e38f;
    #pragma unroll
    for (int cc = 0; cc < 8; ++cc){
      float4 u = xp[cc];
      xv[cc*4+0] = u.x; xv[cc*4+1] = u.y; xv[cc*4+2] = u.z; xv[cc*4+3] = u.w;
      vmin = fminf(vmin, fminf(fminf(u.x,u.y), fminf(u.z,u.w)));
      vmax = fmaxf(vmax, fmaxf(fmaxf(u.x,u.y), fmaxf(u.z,u.w)));
    }
    #pragma unroll
    for (int m = 1; m < 8; m <<= 1){
      vmin = fminf(vmin, __shfl_xor(vmin, m));
      vmax = fmaxf(vmax, __shfl_xor(vmax, m));
    }
    const float sc = PI_HALF / (vmax - vmin + 1e-6f);
    const bool mine = dir ? (c >= 4) : (c < 4);
    if (mine){
      const int s0 = 32*c - (dir ? 128 : 0);   // local site base 0..96
      #pragma unroll
      for (int j = 0; j < 32; ++j){
        float a = (xv[j] - vmin) * sc;
        phiL[(s0 + j)*PHI_S + row] = pack2h(__cosf(a), __sinf(a));
      }
    }
  }
  __syncthreads();

  // ---- State init (buf 0) + first B/A prefetch ----
  uint4 F0[8], F1[8];    // streamed operand ping-pong: [pl*4 + kt]
  if (dir == 0){
    // init: L1[b][l] = c0(b)*first0[l] + s0(b)*first1[l]
    // wave w writes frags (mt = w>>1, kt = 2*(w&1)+c)
    const int mt = w >> 1;
    #pragma unroll
    for (int cc = 0; cc < 2; ++cc){
      const int kt = 2*(w & 1) + cc;
      const int m  = 16*mt + r;
      h2 p0 = __builtin_bit_cast(h2, phiL[0*PHI_S + m]);
      const float c0 = (float)p0[0], s0 = (float)p0[1];
      uint4 o; unsigned ow[4];
      #pragma unroll
      for (int jp = 0; jp < 4; ++jp){
        const int k = 32*kt + 8*q + 2*jp;
        float v0 = first[k]  *c0 + first[128+k]  *s0;
        float v1 = first[k+1]*c0 + first[128+k+1]*s0;
        ow[jp] = pack2h(v0, v1);
      }
      o.x=ow[0]; o.y=ow[1]; o.z=ow[2]; o.w=ow[3];
      *(uint4*)&Ast[((mt*4 + kt)*64 + physL)*4] = o;
    }
    // prefetch B(site 0)
    const uint4* bp = (const uint4*)wsBv;
    #pragma unroll
    for (int pl = 0; pl < 2; ++pl)
      #pragma unroll
      for (int kt = 0; kt < 4; ++kt)
        F0[pl*4+kt] = bp[(size_t)((pl*4 + kt)*8 + w)*64 + lane];
  } else {
    // init: R254[k][b] = lastw[k][0]*c255(b) + lastw[k][1]*s255(b)
    // wave w writes frags (kt = w>>1, nt = 2*(w&1)+c)
    const int kt = w >> 1;
    #pragma unroll
    for (int cc = 0; cc < 2; ++cc){
      const int nt = 2*(w & 1) + cc;
      const int n  = 16*nt + r;
      h2 p5 = __builtin_bit_cast(h2, phiL[127*PHI_S + n]);
      const float cb = (float)p5[0], sb = (float)p5[1];
      uint4 o; unsigned ow[4];
      #pragma unroll
      for (int jp = 0; jp < 4; ++jp){
        const int k = 32*kt + 8*q + 2*jp;
        float2 g0 = *(const float2*)(lastw + 2*k);
        float2 g1 = *(const float2*)(lastw + 2*(k+1));
        ow[jp] = pack2h(g0.x*cb + g0.y*sb, g1.x*cb + g1.y*sb);
      }
      o.x=ow[0]; o.y=ow[1]; o.z=ow[2]; o.w=ow[3];
      *(uint4*)&Ast[((kt*4 + nt)*64 + physL)*4] = o;
    }
    // prefetch A (mid 253 -> srel 126)
    const uint4* bp = (const uint4*)wsBv + TOFF_U4 + (size_t)126 * SITE_U4;
    #pragma unroll
    for (int pl = 0; pl < 2; ++pl)
      #pragma unroll
      for (int kt = 0; kt < 4; ++kt)
        F0[pl*4+kt] = bp[(size_t)((pl*8 + w)*4 + kt)*64 + lane];
  }

  float* Lout = ws_out + LOUT_F32;
  float* Rout = ws_out + ROUT_F32;

  auto body = [&](int s, uint4 (&Fc)[8], uint4 (&Fn)[8]){
    __syncthreads();   // state frags for step s visible; prev-buf reads done

    // prefetch streamed operand for step s+1
    if (dir == 0){
      const int soff = (s < 126) ? (s + 1) : 0;
      const uint4* bp = (const uint4*)wsBv + (size_t)soff * SITE_U4;
      #pragma unroll
      for (int pl = 0; pl < 2; ++pl)
        #pragma unroll
        for (int kt = 0; kt < 4; ++kt)
          Fn[pl*4+kt] = bp[(size_t)((pl*4 + kt)*8 + w)*64 + lane];
    } else {
      const int srel = (s < 126) ? (125 - s) : 0;
      const uint4* bp = (const uint4*)wsBv + TOFF_U4 + (size_t)srel * SITE_U4;
      #pragma unroll
      for (int pl = 0; pl < 2; ++pl)
        #pragma unroll
        for (int kt = 0; kt < 4; ++kt)
          Fn[pl*4+kt] = bp[(size_t)((pl*8 + w)*4 + kt)*64 + lane];
    }

    v4f acc[4][2] = {};   // fwd: [mt][pl] rows 16mt+4q+reg, col 16w+r
                          // bwd: [nt][pl] rows 16w+4q+reg (l), col 16nt+r (b)
    const unsigned* Sb = &Ast[(s & 1) * 4096];
    #pragma unroll
    for (int kt = 0; kt < 4; ++kt){
      if (dir == 0){
        #pragma unroll
        for (int mt = 0; mt < 4; ++mt){
          uint4 a = *(const uint4*)&Sb[((mt*4 + kt)*64 + physL)*4];
          acc[mt][0] = mfma16h(a, Fc[0*4+kt], acc[mt][0]);
          acc[mt][1] = mfma16h(a, Fc[1*4+kt], acc[mt][1]);
        }
      } else {
        #pragma unroll
        for (int nt = 0; nt < 4; ++nt){
          uint4 b = *(const uint4*)&Sb[((kt*4 + nt)*64 + physL)*4];
          acc[nt][0] = mfma16h(Fc[0*4+kt], b, acc[nt][0]);
          acc[nt][1] = mfma16h(Fc[1*4+kt], b, acc[nt][1]);
        }
      }
    }

    if (s < 126){
      unsigned short* Wb = (unsigned short*)&Ast[((s+1) & 1) * 4096];
      if (dir == 0){
        // dest frag (mt'=mt, kt'=w>>1); S = 32(w&1)+16rh+4q+reg; j = r&7
        const int X  = 4*(w & 1) + 2*rh + (q >> 1);
        const int S0 = 32*(w & 1) + 16*rh + 4*q;
        #pragma unroll
        for (int mt = 0; mt < 4; ++mt){
          uint4 phiu = *(const uint4*)&phiL[(s+1)*PHI_S + 16*mt + 4*q];
          const unsigned pr[4] = {phiu.x, phiu.y, phiu.z, phiu.w};
          const int base = (mt*4 + (w >> 1))*512;
          #pragma unroll
          for (int reg = 0; reg < 4; ++reg){
            h2 ph = __builtin_bit_cast(h2, pr[reg]);
            float v = (float)ph[0]*acc[mt][0][reg] + (float)ph[1]*acc[mt][1][reg];
            Wb[base + ((S0 + reg) ^ X)*8 + (r & 7)] = f16b(v);
          }
        }
      } else {
        // phi idx ps=254-s; dest frag (kt'=w>>1, nt'=nt);
        // S = 32(w&1)+16(q>>1)+r; j = 4(q&1)+reg
        const int ps = 254 - s;
        const int X  = 4*(w & 1) + 2*(q >> 1) + rh;
        const int S  = (32*(w & 1) + 16*(q >> 1) + r) ^ X;
        #pragma unroll
        for (int nt = 0; nt < 4; ++nt){
          h2 ph = __builtin_bit_cast(h2, phiL[(ps-128)*PHI_S + 16*nt + r]);
          const float cb = (float)ph[0], sb = (float)ph[1];
          const int base = ((w >> 1)*4 + nt)*512 + S*8 + 4*(q & 1);
          #pragma unroll
          for (int reg = 0; reg < 4; ++reg){
            float v = cb*acc[nt][0][reg] + sb*acc[nt][1][reg];
            Wb[base + reg] = f16b(v);
          }
        }
      }
    } else {
      if (dir == 0){
        // apply phi[127], store Lout[row][l] f32
        #pragma unroll
        for (int mt = 0; mt < 4; ++mt){
          uint4 phiu = *(const uint4*)&phiL[127*PHI_S + 16*mt + 4*q];
          const unsigned pr[4] = {phiu.x, phiu.y, phiu.z, phiu.w};
          #pragma unroll
          for (int reg = 0; reg < 4; ++reg){
            h2 ph = __builtin_bit_cast(h2, pr[reg]);
            float v = (float)ph[0]*acc[mt][0][reg] + (float)ph[1]*acc[mt][1][reg];
            Lout[(size_t)(rowbase + 16*mt + 4*q + reg)*128 + 16*w + r] = v;
          }
        }
      } else {
        // apply phi[128], store RoutT[rg][b][l] f32 (float4 along l)
        #pragma unroll
        for (int nt = 0; nt < 4; ++nt){
          h2 ph = __builtin_bit_cast(h2, phiL[0*PHI_S + 16*nt + r]);
          const float cb = (float)ph[0], sb = (float)ph[1];
          float4 vv;
          vv.x = cb*acc[nt][0][0] + sb*acc[nt][1][0];
          vv.y = cb*acc[nt][0][1] + sb*acc[nt][1][1];
          vv.z = cb*acc[nt][0][2] + sb*acc[nt][1][2];
          vv.w = cb*acc[nt][0][3] + sb*acc[nt][1][3];
          *(float4*)(Rout + (size_t)rg*8192 + (16*nt + r)*128 + 16*w + 4*q) = vv;
        }
      }
    }
  };

  #pragma unroll 1
  for (int s = 0; s < 126; s += 2){
    body(s,     F0, F1);
    body(s + 1, F1, F0);
  }
  body(126, F0, F1);
}

// ---------------------------------------------------------------------------
// Combine: scalar[b] = sum_l Lout[b][l]*RoutT[b>>6][b&63][l]; logits = s*w + bias
// 128 WGs x 256 threads, 4 threads per row.
// ---------------------------------------------------------------------------
__global__ __launch_bounds__(256) void combine(const float* __restrict__ ws,
                                               const float* __restrict__ wlin,
                                               const float* __restrict__ blin,
                                               float* __restrict__ out){
  const int t   = blockIdx.x * 256 + threadIdx.x;
  const int row = t >> 2;
  const int c   = t & 3;
  const float* Lp = ws + LOUT_F32 + (size_t)row*128 + c*32;
  const float* Rp = ws + ROUT_F32 + (size_t)(row >> 6)*8192 + (row & 63)*128 + c*32;
  float s = 0.0f;
  #pragma unroll
  for (int i = 0; i < 8; ++i){
    float4 a = ((const float4*)Lp)[i];
    float4 b = ((const float4*)Rp)[i];
    s += a.x*b.x + a.y*b.y + a.z*b.z + a.w*b.w;
  }
  s += __shfl_xor(s, 1);
  s += __shfl_xor(s, 2);
  if (c == 0){
    #pragma unroll
    for (int o = 0; o < 10; ++o)
      out[(size_t)row*10 + o] = s*wlin[o] + blin[o];
  }
}

extern "C" void kernel_launch(void* const* d_in, const int* in_sizes, int n_in,
                              void* d_out, int out_size, void* d_ws, size_t ws_size,
                              hipStream_t stream){
  (void)in_sizes; (void)n_in; (void)out_size; (void)ws_size;
  const float* x     = (const float*)d_in[0];
  const float* first = (const float*)d_in[1];
  const float* mid   = (const float*)d_in[2];
  const float* lastw = (const float*)d_in[3];
  const float* wlin  = (const float*)d_in[4];
  const float* blin  = (const float*)d_in[5];
  float* o            = (float*)d_out;
  unsigned short* wsB = (unsigned short*)d_ws;   // frags 16.6 MB + Lout/Rout 8 MB

  hipLaunchKernelGGL(repack_mid, dim3(1016), dim3(256), 0, stream, mid, wsB);
  hipLaunchKernelGGL(mps_main,   dim3(256),  dim3(512), 0, stream,
                     x, first, wsB, lastw, (float*)d_ws);
  hipLaunchKernelGGL(combine,    dim3(128),  dim3(256), 0, stream,
                     (const float*)d_ws, wlin, blin, o);
}